// Round 3
// baseline (240.591 us; speedup 1.0000x reference)
//
#include <hip/hip_runtime.h>

#define N 8192
#define DIN 64
#define DOUT 128
#define KNN 16
#define MSAMP 2048         /* presample columns, stride 4 */
#define NBX 8              /* j-split in main scan */
#define CAND_R 64          /* slots per (row, bx) region */
#define CAND_C (NBX * CAND_R)   /* 512 per row */
#define EPS 1.0f           /* candidate-gate margin (passed r8-r11) */
#define DELTA_Q 64         /* verify-gate margin: 0.5 in dist units */
#define VCAP 128           /* verify-list capacity (expect ~45, >10 sigma) */
#define NBLK 512           /* k_scan grid: 2 blocks/CU x 256 CU, co-resident */

typedef unsigned long long u64;
typedef __attribute__((ext_vector_type(8))) short bf16x8;
typedef __attribute__((ext_vector_type(4))) float floatx4;

__device__ __forceinline__ unsigned mono(float f) {
    unsigned u = __float_as_uint(f);
    return (u & 0x80000000u) ? ~u : (u | 0x80000000u);
}
__device__ __forceinline__ unsigned short f2bf(float f) {   // RNE float->bf16
    unsigned u = __float_as_uint(f);
    return (unsigned short)((u + 0x7FFFu + ((u >> 16) & 1u)) >> 16);
}
__device__ __forceinline__ unsigned qdist(float dist) {     // round-up quant
    int q = (int)(dist * 128.0f) + 2;
    q = max(q, 0); return (unsigned)min(q, 65535);
}

// Manual grid barrier (graph-capturable; no cooperative API).  Correct by
// release(fetch_add) -> relaxed agent-scope spin (coherent at L3, no inv
// storm) -> __threadfence acquire (invalidate L1/L2) -> __syncthreads.
// Co-residency: NBLK = 2 blocks/CU exactly (64 KB LDS each), so all blocks
// are resident and the spin cannot starve.
__device__ __forceinline__ void gridbar(unsigned* cnt) {
    __syncthreads();
    if (threadIdx.x == 0) {
        __hip_atomic_fetch_add(cnt, 1u, __ATOMIC_RELEASE, __HIP_MEMORY_SCOPE_AGENT);
        while (__hip_atomic_load(cnt, __ATOMIC_RELAXED, __HIP_MEMORY_SCOPE_AGENT)
               < (unsigned)NBLK)
            __builtin_amdgcn_s_sleep(16);
        __threadfence();    // acquire side: subsequent reads see all blocks' writes
    }
    __syncthreads();
}

// K_SCAN: persistent fusion of [pre | pretau | main].  512 blocks x 512 thr,
// 64 KB LDS union -> exactly 2 blocks/CU.
// Phase PRE:    16 rows/block: sq, sqs, bf16 Xh, U = x@(W1a-W1b)+b1, V = x@W1b.
// Phase PRETAU: rt = b: MFMA vs 2048 sampled cols -> quantized q in LDS
//               (XOR-swizzled slots) -> per-row radix-select tau.
// Phase MAIN:   bx = b&7, 8 waves share one j-tile (staging traffic halved
//               vs the 4-wave standalone kernel); ballot-prefix cand append.
__global__ __launch_bounds__(512, 4) void k_scan(
    const float* __restrict__ x, const float* __restrict__ W1,
    const float* __restrict__ b1, float* __restrict__ sq,
    float* __restrict__ sqs, unsigned short* __restrict__ Xh,
    float* __restrict__ U, float* __restrict__ V,
    float* __restrict__ tauf, unsigned* __restrict__ cand,
    unsigned* __restrict__ cntpart, unsigned* __restrict__ bar)
{
    __shared__ __align__(16) unsigned char smem[65536];   // union of all phases
    int t = threadIdx.x;
    int b = blockIdx.x;

    // ---------------- phase PRE: rows [b*16, b*16+16) ----------------
    {
        float (*xs)[DIN] = (float (*)[DIN])smem;          // 4 KB
        int r0 = b * 16;
        if (t < 256) {
            float4 xv = ((const float4*)x)[(size_t)r0 * (DIN / 4) + t];
            ((float4*)xs)[t] = xv;
            ushort4 h4;
            h4.x = f2bf(xv.x); h4.y = f2bf(xv.y);
            h4.z = f2bf(xv.z); h4.w = f2bf(xv.w);
            *(ushort4*)&Xh[r0 * DIN + t * 4] = h4;
        }
        __syncthreads();
        if (t < 16) {
            const float4* xr = (const float4*)xs[t];
            float s0 = 0.f, s1 = 0.f, s2 = 0.f, s3 = 0.f;
#pragma unroll
            for (int q = 0; q < DIN / 4; ++q) {
                float4 a = xr[q];
                s0 = fmaf(a.x, a.x, s0); s1 = fmaf(a.y, a.y, s1);
                s2 = fmaf(a.z, a.z, s2); s3 = fmaf(a.w, a.w, s3);
            }
            float sv = (s0 + s1) + (s2 + s3);
            sq[r0 + t] = sv;
            if ((t & 3) == 0) sqs[(r0 + t) >> 2] = sv;    // sampled j = 4*scol
        }
        int o = t & 127, g = t >> 7;                      // g in [0,4): 4 rows each
        float aU[4], aV[4];
#pragma unroll
        for (int u = 0; u < 4; ++u) { aU[u] = 0.f; aV[u] = 0.f; }
        for (int kk = 0; kk < DIN; ++kk) {
            float whi = W1[kk * DOUT + o];
            float wlo = W1[(DIN + kk) * DOUT + o];
            float wd = whi - wlo;
#pragma unroll
            for (int u = 0; u < 4; ++u) {
                float xvv = xs[g * 4 + u][kk];
                aU[u] = fmaf(xvv, wd, aU[u]);
                aV[u] = fmaf(xvv, wlo, aV[u]);
            }
        }
        float bb = b1[o];
#pragma unroll
        for (int u = 0; u < 4; ++u) {
            int r = r0 + g * 4 + u;
            U[(size_t)r * DOUT + o] = aU[u] + bb;
            V[(size_t)r * DOUT + o] = aV[u];
        }
    }
    gridbar(bar);
    // ---------------- phase PRETAU: rt = b ----------------
    {
        unsigned short* qls = (unsigned short*)smem;      // 16 x 2048 = 64 KB
        int w = t >> 6, l = t & 63;
        int m = l & 15, quad = l >> 4, ko = quad * 8;
        int irow = b * 16 + m;
        size_t arow = (size_t)irow * DIN;
        bf16x8 iH0 = *(const bf16x8*)(Xh + arow + ko);    // i-row frag (B)
        bf16x8 iH1 = *(const bf16x8*)(Xh + arow + 32 + ko);
        float si = sq[irow];
        int swz = (m & 7) << 4;
        for (int it = 0; it < 16; ++it) {
            int s16 = w * 256 + it * 16;                  // scol tile base
            size_t srowA = (size_t)(4 * (s16 + m)) * DIN; // sampled row (A)
            bf16x8 sH0 = *(const bf16x8*)(Xh + srowA + ko);
            bf16x8 sH1 = *(const bf16x8*)(Xh + srowA + 32 + ko);
            floatx4 acc = {0.f, 0.f, 0.f, 0.f};
            acc = __builtin_amdgcn_mfma_f32_16x16x32_bf16(sH0, iH0, acc, 0, 0, 0);
            acc = __builtin_amdgcn_mfma_f32_16x16x32_bf16(sH1, iH1, acc, 0, 0, 0);
            int sc0 = s16 + quad * 4;                     // 4 consecutive scols
            float4 sj = *(const float4*)(sqs + sc0);
            unsigned q0 = qdist(fmaf(-2.0f, acc[0], si + sj.x));
            unsigned q1 = qdist(fmaf(-2.0f, acc[1], si + sj.y));
            unsigned q2 = qdist(fmaf(-2.0f, acc[2], si + sj.z));
            unsigned q3 = qdist(fmaf(-2.0f, acc[3], si + sj.w));
            u64 pk = (u64)q0 | ((u64)q1 << 16) | ((u64)q2 << 32) | ((u64)q3 << 48);
            *(u64*)&qls[m * MSAMP + (sc0 ^ swz)] = pk;    // multiset-preserving
        }
        __syncthreads();
#pragma unroll
        for (int rr = 0; rr < 2; ++rr) {                  // wave w: rows {2w,2w+1}
            int rsub = w * 2 + rr;
            unsigned v[MSAMP / 64];
#pragma unroll
            for (int u = 0; u < MSAMP / 64; ++u)
                v[u] = qls[rsub * MSAMP + l + 64 * u];
            unsigned p = 0;                               // #{q < p} < 16
#pragma unroll
            for (int bb = 15; bb >= 0; --bb) {
                unsigned c16 = p | (1u << bb);
                int cnt = 0;
#pragma unroll
                for (int u = 0; u < MSAMP / 64; ++u)
                    cnt += __popcll(__ballot(v[u] < c16));
                if (cnt < 16) p = c16;                    // wave-uniform
            }
            if (l == 0) tauf[b * 16 + rsub] = (float)p * (1.0f / 128.0f);
        }
    }
    gridbar(bar + 1);
    // ---------------- phase MAIN: bx = b&7, rt = (b>>3)*8 + w ----------------
    {
        short* ldsH = (short*)smem;                       // 64 x 72 shorts
        int w = t >> 6, l = t & 63;
        int m = l & 15, ko = (l >> 4) * 8;
        int bx = b & 7;
        int rt = (b >> 3) * 8 + w;
        size_t arow = (size_t)(rt * 16 + m) * DIN;
        bf16x8 aH0 = *(const bf16x8*)(Xh + arow + ko);
        bf16x8 aH1 = *(const bf16x8*)(Xh + arow + 32 + ko);
        int rg[4]; float T[4]; float si[4]; int rowcnt[4];
#pragma unroll
        for (int reg = 0; reg < 4; ++reg) {
            rg[reg] = rt * 16 + (l >> 4) * 4 + reg;
            si[reg] = sq[rg[reg]];
            T[reg] = tauf[rg[reg]] + EPS - si[reg];
            rowcnt[reg] = 0;
        }
        int qs = l & 48;
        unsigned lmask = (1u << (l & 15)) - 1u;
        int srw = t >> 3, scol8 = (t & 7) * 8;            // 512 thr: 1 store each

        for (int st = 0; st < 16; ++st) {
            int jbase = bx * 1024 + st * 64;
            __syncthreads();
            *(bf16x8*)&ldsH[srw * 72 + scol8] =
                *(const bf16x8*)(Xh + (size_t)(jbase + srw) * DIN + scol8);
            __syncthreads();
#pragma unroll
            for (int it = 0; it < 4; ++it) {
                int br = it * 16 + m;
                bf16x8 bH0 = *(const bf16x8*)&ldsH[br * 72 + ko];
                bf16x8 bH1 = *(const bf16x8*)&ldsH[br * 72 + 32 + ko];
                floatx4 acc = {0.f, 0.f, 0.f, 0.f};
                acc = __builtin_amdgcn_mfma_f32_16x16x32_bf16(aH0, bH0, acc, 0, 0, 0);
                acc = __builtin_amdgcn_mfma_f32_16x16x32_bf16(aH1, bH1, acc, 0, 0, 0);
                int jcol = jbase + it * 16 + m;
                float sqj = sq[jcol];
#pragma unroll
                for (int reg = 0; reg < 4; ++reg) {
                    float tv = fmaf(-2.0f, acc[reg], sqj);   // dist - si
                    bool pass = tv <= T[reg];
                    u64 bal = __ballot(pass);
                    if (bal) {                               // skip empty (~69%)
                        unsigned m16 = (unsigned)((bal >> qs) & 0xFFFFull);
                        if (pass) {
                            int slot = rowcnt[reg] + __popc(m16 & lmask);
                            if (slot < CAND_R)
                                cand[(size_t)rg[reg] * CAND_C + bx * CAND_R + slot] =
                                    (qdist(tv + si[reg]) << 16) | (unsigned)jcol;
                        }
                        rowcnt[reg] += __popc(m16);
                    }
                }
            }
        }
        if ((l & 15) == 0) {
#pragma unroll
            for (int reg = 0; reg < 4; ++reg)
                cntpart[rg[reg] * NBX + bx] = (unsigned)min(rowcnt[reg], CAND_R);
        }
    }
}

// K_POST: fused [exact | aggout] for the same 4 rows/block.  knn stays in
// LDS (global knn buffer + round-trip eliminated).  Phase E output and
// phase A accumulation orders preserved exactly -> bit-identical result.
__global__ __launch_bounds__(256) void k_post(
    const float* __restrict__ x, const float* __restrict__ sq,
    const unsigned* __restrict__ cntpart, const unsigned* __restrict__ cand,
    const float* __restrict__ U, const float* __restrict__ V,
    const float* __restrict__ W2, const float* __restrict__ b2,
    float* __restrict__ out)
{
    __shared__ union {
        struct { unsigned cj[4][CAND_C];                  // 8 KB
                 unsigned short vlist[4][VCAP];           // 1 KB
                 u64 ekeys[4][VCAP]; } e;                 // 4 KB
        struct { float ag[4][DOUT];                       // 2 KB
                 float w2t[32 * DOUT]; } a;               // 16 KB
    } sm;
    __shared__ int knn_s[4][KNN];                         // survives both phases
    int t = threadIdx.x;
    int w = t >> 6, l = t & 63;
    int row = blockIdx.x * 4 + w;
    // ---------------- phase E: exact top-16 ----------------
    {
        int base = 0;
#pragma unroll
        for (int b = 0; b < NBX; ++b) {                   // compact candidates
            int c = (int)cntpart[row * NBX + b];          // wave-uniform
            c = min(c, CAND_R);
            if (l < c) sm.e.cj[w][base + l] =
                cand[(size_t)row * CAND_C + b * CAND_R + l];
            base += c;
        }
        __syncthreads();
        unsigned kk[CAND_C / 64], qq[CAND_C / 64];
#pragma unroll
        for (int u = 0; u < CAND_C / 64; ++u) {
            int idx = l + 64 * u;
            kk[u] = (idx < base) ? sm.e.cj[w][idx] : 0xFFFFFFFFu;
            qq[u] = (idx < base) ? (kk[u] >> 16) : 0xFFFFFFFFu;
        }
        unsigned p = 0;                                   // radix-select q16
#pragma unroll
        for (int b = 15; b >= 0; --b) {
            unsigned c16 = p | (1u << b);
            int cnt = 0;
#pragma unroll
            for (int u = 0; u < CAND_C / 64; ++u)
                cnt += __popcll(__ballot(qq[u] < c16));
            if (cnt < 16) p = c16;
        }
        unsigned thr = p + DELTA_Q;                       // verify gate on q
        int nv = 0;
        u64 lm = (l == 63) ? 0xFFFFFFFFFFFFFFFFull >> 1 : (1ull << l) - 1ull;
#pragma unroll
        for (int u = 0; u < CAND_C / 64; ++u) {
            bool pred = qq[u] <= thr;                     // invalid qq -> false
            u64 bal = __ballot(pred);
            int slot = nv + __popcll(bal & lm);
            if (pred && slot < VCAP)
                sm.e.vlist[w][slot] = (unsigned short)(kk[u] & 0xFFFFu);
            nv += __popcll(bal);
        }
        nv = min(nv, VCAP);
        __syncthreads();
        float sqi = sq[row];
        const float* xi = x + (size_t)row * DIN;          // wave-uniform
#pragma unroll
        for (int r = 0; r < VCAP / 64; ++r) {
            int v = l + 64 * r;
            if (v < nv) {
                int j = (int)sm.e.vlist[w][v];
                const float4* bj = (const float4*)(x + (size_t)j * DIN);
                float4 rb[16];
#pragma unroll
                for (int q = 0; q < DIN / 4; ++q) rb[q] = bj[q];
                float s0 = 0.f, s1 = 0.f, s2 = 0.f, s3 = 0.f;
#pragma unroll
                for (int q = 0; q < DIN / 4; ++q) {       // striped == r1-r11
                    s0 = fmaf(xi[4 * q + 0], rb[q].x, s0);
                    s1 = fmaf(xi[4 * q + 1], rb[q].y, s1);
                    s2 = fmaf(xi[4 * q + 2], rb[q].z, s2);
                    s3 = fmaf(xi[4 * q + 3], rb[q].w, s3);
                }
                float d = (s0 + s1) + (s2 + s3);
                float dist = fmaf(-2.0f, d, sqi + sq[j]);
                sm.e.ekeys[w][v] = ((u64)mono(dist) << 32) | (unsigned)j;
            }
        }
#pragma unroll
        for (int r = 0; r < VCAP / 64; ++r) {             // all-pairs rank
            int v = l + 64 * r;
            if (v < nv) {
                u64 mykey = sm.e.ekeys[w][v];
                int rank = 0;
                for (int i = 0; i < nv; ++i)
                    rank += (sm.e.ekeys[w][i] < mykey) ? 1 : 0;
                if (rank < KNN)
                    knn_s[w][rank] = (int)(unsigned)(mykey & 0xFFFFFFFFull);
            }
        }
    }
    __syncthreads();                                      // e.* dead after this
    // ---------------- phase A: agg + W2 GEMM ----------------
    {
        int o = t & 127, g = t >> 7;                      // g in {0,1}: 2 rows
        int row0 = blockIdx.x * 4;
#pragma unroll
        for (int r = 0; r < 2; ++r) {
            int rr = g * 2 + r;
            int i = row0 + rr;
            float u = U[(size_t)i * DOUT + o];
            float acc = 0.f;
#pragma unroll
            for (int q = 0; q < KNN; ++q)                 // same q-order as ref
                acc += fmaxf(u + V[(size_t)knn_s[rr][q] * DOUT + o], 0.0f);
            sm.a.ag[rr][o] = acc * (1.0f / KNN);
        }
        float a2[2] = {0.f, 0.f};
#pragma unroll
        for (int tile = 0; tile < 4; ++tile) {
            __syncthreads();
#pragma unroll
            for (int u = 0; u < 4; ++u)                   // 16 KB coalesced stage
                ((float4*)sm.a.w2t)[t + u * 256] =
                    ((const float4*)(W2 + tile * 32 * DOUT))[t + u * 256];
            __syncthreads();
#pragma unroll 8
            for (int kk = 0; kk < 32; ++kk) {
                float wv = sm.a.w2t[kk * DOUT + o];
#pragma unroll
                for (int r = 0; r < 2; ++r)
                    a2[r] = fmaf(sm.a.ag[g * 2 + r][tile * 32 + kk], wv, a2[r]);
            }
        }
        float bb = b2[o];
#pragma unroll
        for (int r = 0; r < 2; ++r)
            out[(size_t)(row0 + g * 2 + r) * DOUT + o] = a2[r] + bb;
    }
}

extern "C" void kernel_launch(void* const* d_in, const int* in_sizes, int n_in,
                              void* d_out, int out_size, void* d_ws, size_t ws_size,
                              hipStream_t stream) {
    const float* x  = (const float*)d_in[0];
    const float* W1 = (const float*)d_in[1];
    const float* b1 = (const float*)d_in[2];
    const float* W2 = (const float*)d_in[3];
    const float* b2 = (const float*)d_in[4];
    float* out = (float*)d_out;

    char* ws = (char*)d_ws;
    float*          sq      = (float*)(ws);                      // 32 KB
    float*          sqs     = (float*)(ws + 32768);              // 8 KB
    float*          tauf    = (float*)(ws + 40960);              // 32 KB
    unsigned*       bar     = (unsigned*)(ws + 73728);           // 8 B (2 counters)
    unsigned short* Xh      = (unsigned short*)(ws + 655360);    // 1 MB
    unsigned*       cntpart = (unsigned*)(ws + 1703936);         // 256 KB
    float*          U       = (float*)(ws + 2097152);            // 4 MB
    float*          V       = (float*)(ws + 6291456);            // 4 MB
    unsigned*       cand    = (unsigned*)(ws + 10485760);        // 16 MB
    // total ws use ~26 MB

    hipMemsetAsync(bar, 0, 8, stream);                           // zero barriers
    k_scan<<<NBLK, 512, 0, stream>>>(x, W1, b1, sq, sqs, Xh, U, V,
                                     tauf, cand, cntpart, bar);
    k_post<<<N / 4, 256, 0, stream>>>(x, sq, cntpart, cand, U, V, W2, b2, out);
}

// Round 4
// 185.527 us; speedup vs baseline: 1.2968x; 1.2968x over previous
//
#include <hip/hip_runtime.h>

#define N 8192
#define DIN 64
#define DOUT 128
#define KNN 16
#define MSAMP 2048         /* presample columns, stride 4 */
#define NBX 16             /* j-split in main scan (512 j per region) */
#define NST 8              /* stages per block: NST*64 = 512 j */
#define CAND_R 64          /* slots per (row, bx) region */
#define CAND_C (NBX * CAND_R)   /* 1024 per row */
#define EPS 1.0f           /* candidate-gate margin (passed r8-r11) */
#define DELTA_Q 64         /* verify-gate margin: 0.5 in dist units */
#define VCAP 128           /* verify-list capacity (expect ~45, >10 sigma) */
#define ROWS_PRE 16

typedef unsigned long long u64;
typedef __attribute__((ext_vector_type(8))) short bf16x8;
typedef __attribute__((ext_vector_type(4))) float floatx4;

__device__ __forceinline__ unsigned mono(float f) {
    unsigned u = __float_as_uint(f);
    return (u & 0x80000000u) ? ~u : (u | 0x80000000u);
}
__device__ __forceinline__ unsigned short f2bf(float f) {   // RNE float->bf16
    unsigned u = __float_as_uint(f);
    return (unsigned short)((u + 0x7FFFu + ((u >> 16) & 1u)) >> 16);
}
__device__ __forceinline__ unsigned qdist(float dist) {     // round-up quant
    int q = (int)(dist * 128.0f) + 2;
    q = max(q, 0); return (unsigned)min(q, 65535);
}

// K1: fused pre: sq, sqs, bf16 Xh, U = x@(W1a-W1b)+b1, V = x@W1b.
__global__ __launch_bounds__(256) void k_pre(const float* __restrict__ x,
                                             const float* __restrict__ W1,
                                             const float* __restrict__ b1,
                                             float* __restrict__ sq,
                                             float* __restrict__ sqs,
                                             unsigned short* __restrict__ Xh,
                                             float* __restrict__ U,
                                             float* __restrict__ V) {
    __shared__ float xs[ROWS_PRE][DIN];
    int t = threadIdx.x;
    int r0 = blockIdx.x * ROWS_PRE;
    float4 xv = ((const float4*)x)[(size_t)r0 * (DIN / 4) + t];
    ((float4*)xs)[t] = xv;
    ushort4 h4;
    h4.x = f2bf(xv.x); h4.y = f2bf(xv.y);
    h4.z = f2bf(xv.z); h4.w = f2bf(xv.w);
    *(ushort4*)&Xh[r0 * DIN + t * 4] = h4;
    __syncthreads();
    if (t < ROWS_PRE) {
        const float4* xr = (const float4*)xs[t];
        float s0 = 0.f, s1 = 0.f, s2 = 0.f, s3 = 0.f;
#pragma unroll
        for (int q = 0; q < DIN / 4; ++q) {
            float4 a = xr[q];
            s0 = fmaf(a.x, a.x, s0); s1 = fmaf(a.y, a.y, s1);
            s2 = fmaf(a.z, a.z, s2); s3 = fmaf(a.w, a.w, s3);
        }
        float sv = (s0 + s1) + (s2 + s3);
        sq[r0 + t] = sv;
        if ((t & 3) == 0) sqs[(r0 + t) >> 2] = sv;   // sampled rows j = 4*scol
    }
    int o = t & 127, g = t >> 7;
    float aU[8], aV[8];
#pragma unroll
    for (int u = 0; u < 8; ++u) { aU[u] = 0.f; aV[u] = 0.f; }
    for (int kk = 0; kk < DIN; ++kk) {
        float whi = W1[kk * DOUT + o];
        float wlo = W1[(DIN + kk) * DOUT + o];
        float wd = whi - wlo;
#pragma unroll
        for (int u = 0; u < 8; ++u) {
            float xvv = xs[g * 8 + u][kk];
            aU[u] = fmaf(xvv, wd, aU[u]);
            aV[u] = fmaf(xvv, wlo, aV[u]);
        }
    }
    float bb = b1[o];
#pragma unroll
    for (int u = 0; u < 8; ++u) {
        int r = r0 + g * 8 + u;
        U[(size_t)r * DOUT + o] = aU[u] + bb;
        V[(size_t)r * DOUT + o] = aV[u];
    }
}

// K2: fused presample + tau (R1-verified).  16 i-rows/block, 8 waves split
// the 2048 sampled cols; quantized q -> 64KB LDS (XOR-swizzled slots,
// multiset-preserving) -> per-row radix-select tau.
__global__ __launch_bounds__(512, 4) void k_pretau(const unsigned short* __restrict__ Xh,
                                                   const float* __restrict__ sq,
                                                   const float* __restrict__ sqs,
                                                   float* __restrict__ tauf) {
    __shared__ __align__(16) unsigned short qls[16 * MSAMP];   // 64 KB exactly
    int tid = threadIdx.x, w = tid >> 6, l = tid & 63;
    int m = l & 15, quad = l >> 4, ko = quad * 8;
    int rt = blockIdx.x;
    int irow = rt * 16 + m;
    size_t arow = (size_t)irow * DIN;
    bf16x8 iH0 = *(const bf16x8*)(Xh + arow + ko);        // i-row frag (B)
    bf16x8 iH1 = *(const bf16x8*)(Xh + arow + 32 + ko);
    float si = sq[irow];
    int swz = (m & 7) << 4;
    for (int it = 0; it < 16; ++it) {
        int s16 = w * 256 + it * 16;                      // scol tile base
        size_t srowA = (size_t)(4 * (s16 + m)) * DIN;     // sampled row (A)
        bf16x8 sH0 = *(const bf16x8*)(Xh + srowA + ko);
        bf16x8 sH1 = *(const bf16x8*)(Xh + srowA + 32 + ko);
        floatx4 acc = {0.f, 0.f, 0.f, 0.f};
        acc = __builtin_amdgcn_mfma_f32_16x16x32_bf16(sH0, iH0, acc, 0, 0, 0);
        acc = __builtin_amdgcn_mfma_f32_16x16x32_bf16(sH1, iH1, acc, 0, 0, 0);
        int sc0 = s16 + quad * 4;                         // 4 consecutive scols
        float4 sj = *(const float4*)(sqs + sc0);
        unsigned q0 = qdist(fmaf(-2.0f, acc[0], si + sj.x));
        unsigned q1 = qdist(fmaf(-2.0f, acc[1], si + sj.y));
        unsigned q2 = qdist(fmaf(-2.0f, acc[2], si + sj.z));
        unsigned q3 = qdist(fmaf(-2.0f, acc[3], si + sj.w));
        u64 pk = (u64)q0 | ((u64)q1 << 16) | ((u64)q2 << 32) | ((u64)q3 << 48);
        *(u64*)&qls[m * MSAMP + (sc0 ^ swz)] = pk;
    }
    __syncthreads();
#pragma unroll
    for (int rr = 0; rr < 2; ++rr) {                      // wave w: rows {2w,2w+1}
        int rsub = w * 2 + rr;
        unsigned v[MSAMP / 64];
#pragma unroll
        for (int u = 0; u < MSAMP / 64; ++u)
            v[u] = qls[rsub * MSAMP + l + 64 * u];
        unsigned p = 0;                               // invariant: #{q < p} < 16
#pragma unroll
        for (int b = 15; b >= 0; --b) {
            unsigned c16 = p | (1u << b);
            int cnt = 0;
#pragma unroll
            for (int u = 0; u < MSAMP / 64; ++u)
                cnt += __popcll(__ballot(v[u] < c16));
            if (cnt < 16) p = c16;                    // wave-uniform
        }
        if (l == 0) tauf[rt * 16 + rsub] = (float)p * (1.0f / 128.0f);
    }
}

// K3: MFMA main scan.  NBX=16 j-regions of 512 (NST=8 stages) -> 2048 blocks
// -> 8 blocks/CU at lb(256,8): 2x the resident waves of the lb(256,4)/NBX=8
// version (R3 showed this kernel family is latency-bound with idle pipes).
// Candidate capacity per region unchanged (64 slots for HALF the j-range ->
// strictly safer); candidate multiset identical, selection order-invariant.
__global__ __launch_bounds__(256, 8) void k_main(const unsigned short* __restrict__ Xh,
                                                 const float* __restrict__ sq,
                                                 const float* __restrict__ tauf,
                                                 unsigned* __restrict__ cand,
                                                 unsigned* __restrict__ cntpart) {
    __shared__ __align__(16) short ldsH[64 * 72];
    int tid = threadIdx.x, w = tid >> 6, l = tid & 63;
    int m = l & 15, ko = (l >> 4) * 8;
    int bx = blockIdx.x;
    int rt = blockIdx.y * 4 + w;
    size_t arow = (size_t)(rt * 16 + m) * DIN;
    bf16x8 aH0 = *(const bf16x8*)(Xh + arow + ko);
    bf16x8 aH1 = *(const bf16x8*)(Xh + arow + 32 + ko);
    int rg[4]; float T[4]; float si[4]; int rowcnt[4];
#pragma unroll
    for (int reg = 0; reg < 4; ++reg) {
        rg[reg] = rt * 16 + (l >> 4) * 4 + reg;
        si[reg] = sq[rg[reg]];
        T[reg] = tauf[rg[reg]] + EPS - si[reg];
        rowcnt[reg] = 0;
    }
    int qs = l & 48;
    unsigned lmask = (1u << (l & 15)) - 1u;
    int srw = tid >> 3, scol8 = (tid & 7) * 8;

    for (int st = 0; st < NST; ++st) {
        int jbase = bx * (NST * 64) + st * 64;
        __syncthreads();
        *(bf16x8*)&ldsH[srw * 72 + scol8] =
            *(const bf16x8*)(Xh + (size_t)(jbase + srw) * DIN + scol8);
        *(bf16x8*)&ldsH[(srw + 32) * 72 + scol8] =
            *(const bf16x8*)(Xh + (size_t)(jbase + srw + 32) * DIN + scol8);
        __syncthreads();
#pragma unroll
        for (int it = 0; it < 4; ++it) {
            int br = it * 16 + m;
            bf16x8 bH0 = *(const bf16x8*)&ldsH[br * 72 + ko];
            bf16x8 bH1 = *(const bf16x8*)&ldsH[br * 72 + 32 + ko];
            floatx4 acc = {0.f, 0.f, 0.f, 0.f};
            acc = __builtin_amdgcn_mfma_f32_16x16x32_bf16(aH0, bH0, acc, 0, 0, 0);
            acc = __builtin_amdgcn_mfma_f32_16x16x32_bf16(aH1, bH1, acc, 0, 0, 0);
            int jcol = jbase + it * 16 + m;
            float sqj = sq[jcol];
#pragma unroll
            for (int reg = 0; reg < 4; ++reg) {
                float tv = fmaf(-2.0f, acc[reg], sqj);   // dist - si
                bool pass = tv <= T[reg];
                u64 bal = __ballot(pass);
                if (bal) {                               // skip empty
                    unsigned m16 = (unsigned)((bal >> qs) & 0xFFFFull);
                    if (pass) {
                        int slot = rowcnt[reg] + __popc(m16 & lmask);
                        if (slot < CAND_R)
                            cand[(size_t)rg[reg] * CAND_C + bx * CAND_R + slot] =
                                (qdist(tv + si[reg]) << 16) | (unsigned)jcol;
                    }
                    rowcnt[reg] += __popc(m16);
                }
            }
        }
    }
    if ((l & 15) == 0) {
#pragma unroll
        for (int reg = 0; reg < 4; ++reg)
            cntpart[rg[reg] * NBX + bx] = (unsigned)min(rowcnt[reg], CAND_R);
    }
}

// K4: fused [exact | aggout] (R3-verified).  knn via LDS; phase orders
// preserved exactly -> bit-identical output.
__global__ __launch_bounds__(256) void k_post(
    const float* __restrict__ x, const float* __restrict__ sq,
    const unsigned* __restrict__ cntpart, const unsigned* __restrict__ cand,
    const float* __restrict__ U, const float* __restrict__ V,
    const float* __restrict__ W2, const float* __restrict__ b2,
    float* __restrict__ out)
{
    __shared__ union {
        struct { unsigned cj[4][CAND_C];                  // 16 KB
                 unsigned short vlist[4][VCAP];           // 1 KB
                 u64 ekeys[4][VCAP]; } e;                 // 4 KB
        struct { float ag[4][DOUT];                       // 2 KB
                 float w2t[32 * DOUT]; } a;               // 16 KB
    } sm;
    __shared__ int knn_s[4][KNN];                         // survives both phases
    int t = threadIdx.x;
    int w = t >> 6, l = t & 63;
    int row = blockIdx.x * 4 + w;
    // ---------------- phase E: exact top-16 ----------------
    {
        int base = 0;
#pragma unroll
        for (int b = 0; b < NBX; ++b) {                   // compact candidates
            int c = (int)cntpart[row * NBX + b];          // wave-uniform
            c = min(c, CAND_R);
            if (l < c) sm.e.cj[w][base + l] =
                cand[(size_t)row * CAND_C + b * CAND_R + l];
            base += c;
        }
        __syncthreads();
        unsigned kk[CAND_C / 64], qq[CAND_C / 64];
#pragma unroll
        for (int u = 0; u < CAND_C / 64; ++u) {
            int idx = l + 64 * u;
            kk[u] = (idx < base) ? sm.e.cj[w][idx] : 0xFFFFFFFFu;
            qq[u] = (idx < base) ? (kk[u] >> 16) : 0xFFFFFFFFu;
        }
        unsigned p = 0;                                   // radix-select q16
#pragma unroll
        for (int b = 15; b >= 0; --b) {
            unsigned c16 = p | (1u << b);
            int cnt = 0;
#pragma unroll
            for (int u = 0; u < CAND_C / 64; ++u)
                cnt += __popcll(__ballot(qq[u] < c16));
            if (cnt < 16) p = c16;
        }
        unsigned thr = p + DELTA_Q;                       // verify gate on q
        int nv = 0;
        u64 lm = (l == 63) ? 0xFFFFFFFFFFFFFFFFull >> 1 : (1ull << l) - 1ull;
#pragma unroll
        for (int u = 0; u < CAND_C / 64; ++u) {
            bool pred = qq[u] <= thr;                     // invalid qq -> false
            u64 bal = __ballot(pred);
            int slot = nv + __popcll(bal & lm);
            if (pred && slot < VCAP)
                sm.e.vlist[w][slot] = (unsigned short)(kk[u] & 0xFFFFu);
            nv += __popcll(bal);
        }
        nv = min(nv, VCAP);
        __syncthreads();
        float sqi = sq[row];
        const float* xi = x + (size_t)row * DIN;          // wave-uniform
#pragma unroll
        for (int r = 0; r < VCAP / 64; ++r) {
            int v = l + 64 * r;
            if (v < nv) {
                int j = (int)sm.e.vlist[w][v];
                const float4* bj = (const float4*)(x + (size_t)j * DIN);
                float4 rb[16];
#pragma unroll
                for (int q = 0; q < DIN / 4; ++q) rb[q] = bj[q];
                float s0 = 0.f, s1 = 0.f, s2 = 0.f, s3 = 0.f;
#pragma unroll
                for (int q = 0; q < DIN / 4; ++q) {       // striped == r1-r11
                    s0 = fmaf(xi[4 * q + 0], rb[q].x, s0);
                    s1 = fmaf(xi[4 * q + 1], rb[q].y, s1);
                    s2 = fmaf(xi[4 * q + 2], rb[q].z, s2);
                    s3 = fmaf(xi[4 * q + 3], rb[q].w, s3);
                }
                float d = (s0 + s1) + (s2 + s3);
                float dist = fmaf(-2.0f, d, sqi + sq[j]);
                sm.e.ekeys[w][v] = ((u64)mono(dist) << 32) | (unsigned)j;
            }
        }
#pragma unroll
        for (int r = 0; r < VCAP / 64; ++r) {             // all-pairs rank
            int v = l + 64 * r;
            if (v < nv) {
                u64 mykey = sm.e.ekeys[w][v];
                int rank = 0;
                for (int i = 0; i < nv; ++i)
                    rank += (sm.e.ekeys[w][i] < mykey) ? 1 : 0;
                if (rank < KNN)
                    knn_s[w][rank] = (int)(unsigned)(mykey & 0xFFFFFFFFull);
            }
        }
    }
    __syncthreads();                                      // e.* dead after this
    // ---------------- phase A: agg + W2 GEMM ----------------
    {
        int o = t & 127, g = t >> 7;                      // g in {0,1}: 2 rows
        int row0 = blockIdx.x * 4;
#pragma unroll
        for (int r = 0; r < 2; ++r) {
            int rr = g * 2 + r;
            int i = row0 + rr;
            float u = U[(size_t)i * DOUT + o];
            float acc = 0.f;
#pragma unroll
            for (int q = 0; q < KNN; ++q)                 // same q-order as ref
                acc += fmaxf(u + V[(size_t)knn_s[rr][q] * DOUT + o], 0.0f);
            sm.a.ag[rr][o] = acc * (1.0f / KNN);
        }
        float a2[2] = {0.f, 0.f};
#pragma unroll
        for (int tile = 0; tile < 4; ++tile) {
            __syncthreads();
#pragma unroll
            for (int u = 0; u < 4; ++u)                   // 16 KB coalesced stage
                ((float4*)sm.a.w2t)[t + u * 256] =
                    ((const float4*)(W2 + tile * 32 * DOUT))[t + u * 256];
            __syncthreads();
#pragma unroll 8
            for (int kk = 0; kk < 32; ++kk) {
                float wv = sm.a.w2t[kk * DOUT + o];
#pragma unroll
                for (int r = 0; r < 2; ++r)
                    a2[r] = fmaf(sm.a.ag[g * 2 + r][tile * 32 + kk], wv, a2[r]);
            }
        }
        float bb = b2[o];
#pragma unroll
        for (int r = 0; r < 2; ++r)
            out[(size_t)(row0 + g * 2 + r) * DOUT + o] = a2[r] + bb;
    }
}

extern "C" void kernel_launch(void* const* d_in, const int* in_sizes, int n_in,
                              void* d_out, int out_size, void* d_ws, size_t ws_size,
                              hipStream_t stream) {
    const float* x  = (const float*)d_in[0];
    const float* W1 = (const float*)d_in[1];
    const float* b1 = (const float*)d_in[2];
    const float* W2 = (const float*)d_in[3];
    const float* b2 = (const float*)d_in[4];
    float* out = (float*)d_out;

    char* ws = (char*)d_ws;
    float*          sq      = (float*)(ws);                      // 32 KB
    float*          sqs     = (float*)(ws + 32768);              // 8 KB
    float*          tauf    = (float*)(ws + 40960);              // 32 KB
    unsigned short* Xh      = (unsigned short*)(ws + 655360);    // 1 MB
    float*          U       = (float*)(ws + 2097152);            // 4 MB
    float*          V       = (float*)(ws + 6291456);            // 4 MB
    unsigned*       cntpart = (unsigned*)(ws + 10485760);        // 512 KB
    unsigned*       cand    = (unsigned*)(ws + 11534336);        // 32 MB
    // total ws use ~45 MB (<< 268 MB workspace)

    k_pre<<<N / ROWS_PRE, 256, 0, stream>>>(x, W1, b1, sq, sqs, Xh, U, V);
    k_pretau<<<N / 16, 512, 0, stream>>>(Xh, sq, sqs, tauf);
    k_main<<<dim3(NBX, 128), 256, 0, stream>>>(Xh, sq, tauf, cand, cntpart);
    k_post<<<N / 4, 256, 0, stream>>>(x, sq, cntpart, cand, U, V, W2, b2, out);
}

// Round 5
// 171.727 us; speedup vs baseline: 1.4010x; 1.0804x over previous
//
#include <hip/hip_runtime.h>

#define N 8192
#define DIN 64
#define DOUT 128
#define KNN 16
#define MSAMP 2048         /* presample columns, stride 4 */
#define NBX 16             /* j-split in main scan (512 j per region) */
#define NST 8              /* stages per block: NST*64 = 512 j */
#define CAND_R 64          /* slots per (row, bx) region == wave width */
#define CAND_C (NBX * CAND_R)   /* 1024 per row */
#define EPS 1.0f           /* candidate-gate margin (passed r8-r11) */
#define DELTA_Q 64         /* verify-gate margin: 0.5 in dist units */
#define VCAP 128           /* verify-list capacity (expect ~45, >10 sigma) */
#define ROWS_PRE 16

typedef unsigned long long u64;
typedef __attribute__((ext_vector_type(8))) short bf16x8;
typedef __attribute__((ext_vector_type(4))) float floatx4;

__device__ __forceinline__ unsigned mono(float f) {
    unsigned u = __float_as_uint(f);
    return (u & 0x80000000u) ? ~u : (u | 0x80000000u);
}
__device__ __forceinline__ unsigned short f2bf(float f) {   // RNE float->bf16
    unsigned u = __float_as_uint(f);
    return (unsigned short)((u + 0x7FFFu + ((u >> 16) & 1u)) >> 16);
}
__device__ __forceinline__ unsigned qdist(float dist) {     // round-up quant
    int q = (int)(dist * 128.0f) + 2;
    q = max(q, 0); return (unsigned)min(q, 65535);
}

// K1: fused pre: sq, sqs, bf16 Xh, U = x@(W1a-W1b)+b1, V = x@W1b.
__global__ __launch_bounds__(256) void k_pre(const float* __restrict__ x,
                                             const float* __restrict__ W1,
                                             const float* __restrict__ b1,
                                             float* __restrict__ sq,
                                             float* __restrict__ sqs,
                                             unsigned short* __restrict__ Xh,
                                             float* __restrict__ U,
                                             float* __restrict__ V) {
    __shared__ float xs[ROWS_PRE][DIN];
    int t = threadIdx.x;
    int r0 = blockIdx.x * ROWS_PRE;
    float4 xv = ((const float4*)x)[(size_t)r0 * (DIN / 4) + t];
    ((float4*)xs)[t] = xv;
    ushort4 h4;
    h4.x = f2bf(xv.x); h4.y = f2bf(xv.y);
    h4.z = f2bf(xv.z); h4.w = f2bf(xv.w);
    *(ushort4*)&Xh[r0 * DIN + t * 4] = h4;
    __syncthreads();
    if (t < ROWS_PRE) {
        const float4* xr = (const float4*)xs[t];
        float s0 = 0.f, s1 = 0.f, s2 = 0.f, s3 = 0.f;
#pragma unroll
        for (int q = 0; q < DIN / 4; ++q) {
            float4 a = xr[q];
            s0 = fmaf(a.x, a.x, s0); s1 = fmaf(a.y, a.y, s1);
            s2 = fmaf(a.z, a.z, s2); s3 = fmaf(a.w, a.w, s3);
        }
        float sv = (s0 + s1) + (s2 + s3);
        sq[r0 + t] = sv;
        if ((t & 3) == 0) sqs[(r0 + t) >> 2] = sv;   // sampled rows j = 4*scol
    }
    int o = t & 127, g = t >> 7;
    float aU[8], aV[8];
#pragma unroll
    for (int u = 0; u < 8; ++u) { aU[u] = 0.f; aV[u] = 0.f; }
    for (int kk = 0; kk < DIN; ++kk) {
        float whi = W1[kk * DOUT + o];
        float wlo = W1[(DIN + kk) * DOUT + o];
        float wd = whi - wlo;
#pragma unroll
        for (int u = 0; u < 8; ++u) {
            float xvv = xs[g * 8 + u][kk];
            aU[u] = fmaf(xvv, wd, aU[u]);
            aV[u] = fmaf(xvv, wlo, aV[u]);
        }
    }
    float bb = b1[o];
#pragma unroll
    for (int u = 0; u < 8; ++u) {
        int r = r0 + g * 8 + u;
        U[(size_t)r * DOUT + o] = aU[u] + bb;
        V[(size_t)r * DOUT + o] = aV[u];
    }
}

// K2: fused presample + tau (R1-verified).
__global__ __launch_bounds__(512, 4) void k_pretau(const unsigned short* __restrict__ Xh,
                                                   const float* __restrict__ sq,
                                                   const float* __restrict__ sqs,
                                                   float* __restrict__ tauf) {
    __shared__ __align__(16) unsigned short qls[16 * MSAMP];   // 64 KB exactly
    int tid = threadIdx.x, w = tid >> 6, l = tid & 63;
    int m = l & 15, quad = l >> 4, ko = quad * 8;
    int rt = blockIdx.x;
    int irow = rt * 16 + m;
    size_t arow = (size_t)irow * DIN;
    bf16x8 iH0 = *(const bf16x8*)(Xh + arow + ko);        // i-row frag (B)
    bf16x8 iH1 = *(const bf16x8*)(Xh + arow + 32 + ko);
    float si = sq[irow];
    int swz = (m & 7) << 4;
    for (int it = 0; it < 16; ++it) {
        int s16 = w * 256 + it * 16;                      // scol tile base
        size_t srowA = (size_t)(4 * (s16 + m)) * DIN;     // sampled row (A)
        bf16x8 sH0 = *(const bf16x8*)(Xh + srowA + ko);
        bf16x8 sH1 = *(const bf16x8*)(Xh + srowA + 32 + ko);
        floatx4 acc = {0.f, 0.f, 0.f, 0.f};
        acc = __builtin_amdgcn_mfma_f32_16x16x32_bf16(sH0, iH0, acc, 0, 0, 0);
        acc = __builtin_amdgcn_mfma_f32_16x16x32_bf16(sH1, iH1, acc, 0, 0, 0);
        int sc0 = s16 + quad * 4;                         // 4 consecutive scols
        float4 sj = *(const float4*)(sqs + sc0);
        unsigned q0 = qdist(fmaf(-2.0f, acc[0], si + sj.x));
        unsigned q1 = qdist(fmaf(-2.0f, acc[1], si + sj.y));
        unsigned q2 = qdist(fmaf(-2.0f, acc[2], si + sj.z));
        unsigned q3 = qdist(fmaf(-2.0f, acc[3], si + sj.w));
        u64 pk = (u64)q0 | ((u64)q1 << 16) | ((u64)q2 << 32) | ((u64)q3 << 48);
        *(u64*)&qls[m * MSAMP + (sc0 ^ swz)] = pk;
    }
    __syncthreads();
#pragma unroll
    for (int rr = 0; rr < 2; ++rr) {                      // wave w: rows {2w,2w+1}
        int rsub = w * 2 + rr;
        unsigned v[MSAMP / 64];
#pragma unroll
        for (int u = 0; u < MSAMP / 64; ++u)
            v[u] = qls[rsub * MSAMP + l + 64 * u];
        unsigned p = 0;                               // invariant: #{q < p} < 16
#pragma unroll
        for (int b = 15; b >= 0; --b) {
            unsigned c16 = p | (1u << b);
            int cnt = 0;
#pragma unroll
            for (int u = 0; u < MSAMP / 64; ++u)
                cnt += __popcll(__ballot(v[u] < c16));
            if (cnt < 16) p = c16;                    // wave-uniform
        }
        if (l == 0) tauf[rt * 16 + rsub] = (float)p * (1.0f / 128.0f);
    }
}

// K3: MFMA main scan (R4 geometry: NBX=16, 8 blocks/CU).
__global__ __launch_bounds__(256, 8) void k_main(const unsigned short* __restrict__ Xh,
                                                 const float* __restrict__ sq,
                                                 const float* __restrict__ tauf,
                                                 unsigned* __restrict__ cand,
                                                 unsigned* __restrict__ cntpart) {
    __shared__ __align__(16) short ldsH[64 * 72];
    int tid = threadIdx.x, w = tid >> 6, l = tid & 63;
    int m = l & 15, ko = (l >> 4) * 8;
    int bx = blockIdx.x;
    int rt = blockIdx.y * 4 + w;
    size_t arow = (size_t)(rt * 16 + m) * DIN;
    bf16x8 aH0 = *(const bf16x8*)(Xh + arow + ko);
    bf16x8 aH1 = *(const bf16x8*)(Xh + arow + 32 + ko);
    int rg[4]; float T[4]; float si[4]; int rowcnt[4];
#pragma unroll
    for (int reg = 0; reg < 4; ++reg) {
        rg[reg] = rt * 16 + (l >> 4) * 4 + reg;
        si[reg] = sq[rg[reg]];
        T[reg] = tauf[rg[reg]] + EPS - si[reg];
        rowcnt[reg] = 0;
    }
    int qs = l & 48;
    unsigned lmask = (1u << (l & 15)) - 1u;
    int srw = tid >> 3, scol8 = (tid & 7) * 8;

    for (int st = 0; st < NST; ++st) {
        int jbase = bx * (NST * 64) + st * 64;
        __syncthreads();
        *(bf16x8*)&ldsH[srw * 72 + scol8] =
            *(const bf16x8*)(Xh + (size_t)(jbase + srw) * DIN + scol8);
        *(bf16x8*)&ldsH[(srw + 32) * 72 + scol8] =
            *(const bf16x8*)(Xh + (size_t)(jbase + srw + 32) * DIN + scol8);
        __syncthreads();
#pragma unroll
        for (int it = 0; it < 4; ++it) {
            int br = it * 16 + m;
            bf16x8 bH0 = *(const bf16x8*)&ldsH[br * 72 + ko];
            bf16x8 bH1 = *(const bf16x8*)&ldsH[br * 72 + 32 + ko];
            floatx4 acc = {0.f, 0.f, 0.f, 0.f};
            acc = __builtin_amdgcn_mfma_f32_16x16x32_bf16(aH0, bH0, acc, 0, 0, 0);
            acc = __builtin_amdgcn_mfma_f32_16x16x32_bf16(aH1, bH1, acc, 0, 0, 0);
            int jcol = jbase + it * 16 + m;
            float sqj = sq[jcol];
#pragma unroll
            for (int reg = 0; reg < 4; ++reg) {
                float tv = fmaf(-2.0f, acc[reg], sqj);   // dist - si
                bool pass = tv <= T[reg];
                u64 bal = __ballot(pass);
                if (bal) {                               // skip empty
                    unsigned m16 = (unsigned)((bal >> qs) & 0xFFFFull);
                    if (pass) {
                        int slot = rowcnt[reg] + __popc(m16 & lmask);
                        if (slot < CAND_R)
                            cand[(size_t)rg[reg] * CAND_C + bx * CAND_R + slot] =
                                (qdist(tv + si[reg]) << 16) | (unsigned)jcol;
                    }
                    rowcnt[reg] += __popc(m16);
                }
            }
        }
    }
    if ((l & 15) == 0) {
#pragma unroll
        for (int reg = 0; reg < 4; ++reg)
            cntpart[rg[reg] * NBX + bx] = (unsigned)min(rowcnt[reg], CAND_R);
    }
}

// K4: fused [exact | aggout], COMPACTION-FREE phase E.  CAND_R == 64 == wave
// width -> register u maps 1:1 to region u, lane l to slot l, validity
// l < c[u].  No cj LDS, no serial base+=c chain, cand reads fully coalesced
// (L2-hot).  Radix sees the same multiset; verify's ballot-prefix order is
// region-major/slot-minor == the old stable compaction order -> vlist,
// ekeys, knn, output all bit-identical.  LDS 18.3 KB, lb(256,8): grid 2048
// = 8 blocks/CU exactly resident.
__global__ __launch_bounds__(256, 8) void k_post(
    const float* __restrict__ x, const float* __restrict__ sq,
    const unsigned* __restrict__ cntpart, const unsigned* __restrict__ cand,
    const float* __restrict__ U, const float* __restrict__ V,
    const float* __restrict__ W2, const float* __restrict__ b2,
    float* __restrict__ out)
{
    __shared__ union {
        struct { unsigned short vlist[4][VCAP];           // 1 KB
                 u64 ekeys[4][VCAP]; } e;                 // 4 KB
        struct { float ag[4][DOUT];                       // 2 KB
                 float w2t[32 * DOUT]; } a;               // 16 KB
    } sm;
    __shared__ int knn_s[4][KNN];                         // survives both phases
    int t = threadIdx.x;
    int w = t >> 6, l = t & 63;
    int row = blockIdx.x * 4 + w;
    // ---------------- phase E: exact top-16 ----------------
    {
        unsigned c[NBX];
        const unsigned* cp = cntpart + (size_t)row * NBX; // wave-uniform -> s_load
#pragma unroll
        for (int b = 0; b < NBX; ++b) c[b] = min(cp[b], (unsigned)CAND_R);
        const unsigned* crow = cand + (size_t)row * CAND_C;
        unsigned qq[NBX];
#pragma unroll
        for (int u = 0; u < NBX; ++u) {                   // all loads independent
            unsigned kv = crow[u * 64 + l];               // coalesced 256B/reg
            qq[u] = ((unsigned)l < c[u]) ? (kv >> 16) : 0xFFFFFFFFu;
        }
        unsigned p = 0;                                   // radix-select q16
#pragma unroll
        for (int b = 15; b >= 0; --b) {
            unsigned c16 = p | (1u << b);
            int cnt = 0;
#pragma unroll
            for (int u = 0; u < NBX; ++u)
                cnt += __popcll(__ballot(qq[u] < c16));
            if (cnt < 16) p = c16;
        }
        unsigned thr = p + DELTA_Q;                       // verify gate on q
        int nv = 0;
        u64 lm = (l == 63) ? 0xFFFFFFFFFFFFFFFFull >> 1 : (1ull << l) - 1ull;
#pragma unroll
        for (int u = 0; u < NBX; ++u) {
            bool pred = qq[u] <= thr;                     // invalid qq -> false
            u64 bal = __ballot(pred);
            int slot = nv + __popcll(bal & lm);
            if (pred && slot < VCAP) {
                unsigned kv = crow[u * 64 + l];           // reload j (L1/L2-hot)
                sm.e.vlist[w][slot] = (unsigned short)(kv & 0xFFFFu);
            }
            nv += __popcll(bal);
        }
        nv = min(nv, VCAP);
        __syncthreads();
        float sqi = sq[row];
        const float* xi = x + (size_t)row * DIN;          // wave-uniform
#pragma unroll
        for (int r = 0; r < VCAP / 64; ++r) {
            int v = l + 64 * r;
            if (v < nv) {
                int j = (int)sm.e.vlist[w][v];
                const float4* bj = (const float4*)(x + (size_t)j * DIN);
                float s0 = 0.f, s1 = 0.f, s2 = 0.f, s3 = 0.f;
                float4 rb[8];                             // 2x8 stages: same
#pragma unroll
                for (int q = 0; q < 8; ++q) rb[q] = bj[q];
#pragma unroll
                for (int q = 0; q < 8; ++q) {             // FMA order per acc
                    s0 = fmaf(xi[4 * q + 0], rb[q].x, s0);//  chain == r1-r11
                    s1 = fmaf(xi[4 * q + 1], rb[q].y, s1);
                    s2 = fmaf(xi[4 * q + 2], rb[q].z, s2);
                    s3 = fmaf(xi[4 * q + 3], rb[q].w, s3);
                }
#pragma unroll
                for (int q = 0; q < 8; ++q) rb[q] = bj[8 + q];
#pragma unroll
                for (int q = 0; q < 8; ++q) {
                    s0 = fmaf(xi[32 + 4 * q + 0], rb[q].x, s0);
                    s1 = fmaf(xi[32 + 4 * q + 1], rb[q].y, s1);
                    s2 = fmaf(xi[32 + 4 * q + 2], rb[q].z, s2);
                    s3 = fmaf(xi[32 + 4 * q + 3], rb[q].w, s3);
                }
                float d = (s0 + s1) + (s2 + s3);
                float dist = fmaf(-2.0f, d, sqi + sq[j]);
                sm.e.ekeys[w][v] = ((u64)mono(dist) << 32) | (unsigned)j;
            }
        }
#pragma unroll
        for (int r = 0; r < VCAP / 64; ++r) {             // all-pairs rank
            int v = l + 64 * r;
            if (v < nv) {
                u64 mykey = sm.e.ekeys[w][v];
                int rank = 0;
                for (int i = 0; i < nv; ++i)
                    rank += (sm.e.ekeys[w][i] < mykey) ? 1 : 0;
                if (rank < KNN)
                    knn_s[w][rank] = (int)(unsigned)(mykey & 0xFFFFFFFFull);
            }
        }
    }
    __syncthreads();                                      // e.* dead after this
    // ---------------- phase A: agg + W2 GEMM ----------------
    {
        int o = t & 127, g = t >> 7;                      // g in {0,1}: 2 rows
        int row0 = blockIdx.x * 4;
#pragma unroll
        for (int r = 0; r < 2; ++r) {
            int rr = g * 2 + r;
            int i = row0 + rr;
            float u = U[(size_t)i * DOUT + o];
            float acc = 0.f;
#pragma unroll
            for (int q = 0; q < KNN; ++q)                 // same q-order as ref
                acc += fmaxf(u + V[(size_t)knn_s[rr][q] * DOUT + o], 0.0f);
            sm.a.ag[rr][o] = acc * (1.0f / KNN);
        }
        float a2[2] = {0.f, 0.f};
#pragma unroll
        for (int tile = 0; tile < 4; ++tile) {
            __syncthreads();
#pragma unroll
            for (int u = 0; u < 4; ++u)                   // 16 KB coalesced stage
                ((float4*)sm.a.w2t)[t + u * 256] =
                    ((const float4*)(W2 + tile * 32 * DOUT))[t + u * 256];
            __syncthreads();
#pragma unroll 8
            for (int kk = 0; kk < 32; ++kk) {
                float wv = sm.a.w2t[kk * DOUT + o];
#pragma unroll
                for (int r = 0; r < 2; ++r)
                    a2[r] = fmaf(sm.a.ag[g * 2 + r][tile * 32 + kk], wv, a2[r]);
            }
        }
        float bb = b2[o];
#pragma unroll
        for (int r = 0; r < 2; ++r)
            out[(size_t)(row0 + g * 2 + r) * DOUT + o] = a2[r] + bb;
    }
}

extern "C" void kernel_launch(void* const* d_in, const int* in_sizes, int n_in,
                              void* d_out, int out_size, void* d_ws, size_t ws_size,
                              hipStream_t stream) {
    const float* x  = (const float*)d_in[0];
    const float* W1 = (const float*)d_in[1];
    const float* b1 = (const float*)d_in[2];
    const float* W2 = (const float*)d_in[3];
    const float* b2 = (const float*)d_in[4];
    float* out = (float*)d_out;

    char* ws = (char*)d_ws;
    float*          sq      = (float*)(ws);                      // 32 KB
    float*          sqs     = (float*)(ws + 32768);              // 8 KB
    float*          tauf    = (float*)(ws + 40960);              // 32 KB
    unsigned short* Xh      = (unsigned short*)(ws + 655360);    // 1 MB
    float*          U       = (float*)(ws + 2097152);            // 4 MB
    float*          V       = (float*)(ws + 6291456);            // 4 MB
    unsigned*       cntpart = (unsigned*)(ws + 10485760);        // 512 KB
    unsigned*       cand    = (unsigned*)(ws + 11534336);        // 32 MB
    // total ws use ~45 MB (<< 268 MB workspace)

    k_pre<<<N / ROWS_PRE, 256, 0, stream>>>(x, W1, b1, sq, sqs, Xh, U, V);
    k_pretau<<<N / 16, 512, 0, stream>>>(Xh, sq, sqs, tauf);
    k_main<<<dim3(NBX, 128), 256, 0, stream>>>(Xh, sq, tauf, cand, cntpart);
    k_post<<<N / 4, 256, 0, stream>>>(x, sq, cntpart, cand, U, V, W2, b2, out);
}